// Round 4
// baseline (4584.497 us; speedup 1.0000x reference)
//
#include <hip/hip_runtime.h>
#include <math.h>

#define TPB 512   // 8 waves = 2 waves/SIMD

// rcp + 1 Newton-Raphson step: ~0.5 ulp, 3 inst (1 trans + 2 VALU)
__device__ __forceinline__ float rcp_nr(float x) {
    float r = __builtin_amdgcn_rcpf(x);
    return r * fmaf(-x, r, 2.0f);
}

// Six independent 4-lane-group partial reductions, fused DPP adds (1 inst/step).
// Round-robin interleave gives each register 6-inst spacing (covers the
// VALU-write -> DPP-operand hazard, 2 wait states); s_nop 1 covers entry.
// After this, lanes with (lane&3)==3 hold their 4-lane-group sum.
__device__ __forceinline__ void red6_g4(float& g0, float& g1, float& g2,
                                        float& g3, float& g4, float& g5) {
    asm("s_nop 1\n\t"
        "v_add_f32 %0, %0, %0 row_shr:1 row_mask:0xf bank_mask:0xf bound_ctrl:0\n\t"
        "v_add_f32 %1, %1, %1 row_shr:1 row_mask:0xf bank_mask:0xf bound_ctrl:0\n\t"
        "v_add_f32 %2, %2, %2 row_shr:1 row_mask:0xf bank_mask:0xf bound_ctrl:0\n\t"
        "v_add_f32 %3, %3, %3 row_shr:1 row_mask:0xf bank_mask:0xf bound_ctrl:0\n\t"
        "v_add_f32 %4, %4, %4 row_shr:1 row_mask:0xf bank_mask:0xf bound_ctrl:0\n\t"
        "v_add_f32 %5, %5, %5 row_shr:1 row_mask:0xf bank_mask:0xf bound_ctrl:0\n\t"
        "v_add_f32 %0, %0, %0 row_shr:2 row_mask:0xf bank_mask:0xf bound_ctrl:0\n\t"
        "v_add_f32 %1, %1, %1 row_shr:2 row_mask:0xf bank_mask:0xf bound_ctrl:0\n\t"
        "v_add_f32 %2, %2, %2 row_shr:2 row_mask:0xf bank_mask:0xf bound_ctrl:0\n\t"
        "v_add_f32 %3, %3, %3 row_shr:2 row_mask:0xf bank_mask:0xf bound_ctrl:0\n\t"
        "v_add_f32 %4, %4, %4 row_shr:2 row_mask:0xf bank_mask:0xf bound_ctrl:0\n\t"
        "v_add_f32 %5, %5, %5 row_shr:2 row_mask:0xf bank_mask:0xf bound_ctrl:0"
        : "+v"(g0), "+v"(g1), "+v"(g2), "+v"(g3), "+v"(g4), "+v"(g5));
}

// 4-lane combine for the update stage (lane (tid&3)==3 gets group total)
__device__ __forceinline__ float red1_g4(float g) {
    asm("s_nop 1\n\t"
        "v_add_f32 %0, %0, %0 row_shr:1 row_mask:0xf bank_mask:0xf bound_ctrl:0\n\t"
        "s_nop 1\n\t"
        "v_add_f32 %0, %0, %0 row_shr:2 row_mask:0xf bank_mask:0xf bound_ctrl:0"
        : "+v"(g));
    return g;
}

__global__ __launch_bounds__(TPB, 2)
void sgd_filter(const float* __restrict__ sos_in,
                const float* __restrict__ target,
                float* __restrict__ out) {
    // sections padded to 8 floats: [b0 b1 b2 a0 a1 a2 pad pad]
    __shared__ __align__(16) float sos[16 * 8];
    // 128 4-lane-group partials x (16 sections x 8 cols); stride 132
    // (132 mod 32 = 4): store banks 2-way (free), read banks <=4-way.
    __shared__ __align__(16) float gpart[128][132];

    const int tid = threadIdx.x;

    if (tid < 96) sos[(tid / 6) * 8 + (tid % 6)] = sos_in[tid];

    // Update identity: 4 threads per coefficient u = tid>>2 (tid<384);
    // lane (tid&3)==3 owns the coefficient value.
    const int u = tid >> 2;
    const int chunk = tid & 3;
    const int ucol = (u / 6) * 8 + (u % 6);        // meaningful for tid<384
    const bool upd = (tid < 384);
    const bool writer = upd && ((tid & 3) == 3);
    float myc = 0.0f;
    if (writer) myc = sos_in[u];

    // Per-thread frequency constants
    const float w  = (float)((double)tid * (3.14159265358979323846 / 511.0));
    const float c1 = cosf(w);
    const float s1 = -sinf(w);           // z1 = e^{-jw}
    const float c2 = c1 * c1 - s1 * s1;  // z2 = z1^2
    const float s2 = 2.0f * c1 * s1;
    const float tgt = target[tid];
    const float KC = 40.0f / (512.0f * 2.302585092994046f); // 40/(n*ln10)

    __syncthreads();

    for (int it = 0; it < 1000; ++it) {
        // ---- pass 1: log2|H|^2 accumulation (no state kept per section) ----
        float L = 0.0f;
#pragma unroll
        for (int s = 0; s < 16; ++s) {
            const float4 v0 = *(const float4*)&sos[s * 8];     // b0 b1 b2 a0
            const float2 v1 = *(const float2*)&sos[s * 8 + 4]; // a1 a2
            const float Br = fmaf(v0.z, c2, fmaf(v0.y, c1, v0.x));
            const float Bi = fmaf(v0.z, s2, v0.y * s1);
            const float Ar = fmaf(v1.y, c2, fmaf(v1.x, c1, v0.w));
            const float Ai = fmaf(v1.y, s2, v1.x * s1);
            const float nB = fmaf(Br, Br, Bi * Bi);
            const float nA = fmaf(Ar, Ar, Ai * Ai);
            L += __builtin_amdgcn_logf(nB) - __builtin_amdgcn_logf(nA); // log2
        }
        const float mag   = __builtin_amdgcn_exp2f(0.5f * L);
        const float magpe = mag + 1e-8f;
        const float indB  = 6.020599913279624f * __builtin_amdgcn_logf(magpe); // 20*log10
        const float diff  = indB - tgt;
        const float K  = KC * diff * mag * rcp_nr(magpe);
        const float Kn = -K;

        // ---- pass 2: recompute per section, scale by K, reduce, store ----
#pragma unroll
        for (int s = 0; s < 16; ++s) {
            const float4 v0 = *(const float4*)&sos[s * 8];
            const float2 v1 = *(const float2*)&sos[s * 8 + 4];
            const float Br = fmaf(v0.z, c2, fmaf(v0.y, c1, v0.x));
            const float Bi = fmaf(v0.z, s2, v0.y * s1);
            const float Ar = fmaf(v1.y, c2, fmaf(v1.x, c1, v0.w));
            const float Ai = fmaf(v1.y, s2, v1.x * s1);
            const float nB = fmaf(Br, Br, Bi * Bi);
            const float nA = fmaf(Ar, Ar, Ai * Ai);
            const float Pb = K * rcp_nr(nB);
            const float Pa = Kn * rcp_nr(nA);
            float g0 = Pb * Br;
            float g1 = Pb * fmaf(c1, Br, s1 * Bi);   // Re(z1 conjB)
            float g2 = Pb * fmaf(c2, Br, s2 * Bi);   // Re(z2 conjB)
            float g3 = Pa * Ar;
            float g4 = Pa * fmaf(c1, Ar, s1 * Ai);
            float g5 = Pa * fmaf(c2, Ar, s2 * Ai);
            red6_g4(g0, g1, g2, g3, g4, g5);
            if ((tid & 3) == 3) {                    // 128 group leaders
                float* p = &gpart[tid >> 2][s * 8];
                *(float4*)p       = make_float4(g0, g1, g2, g3);
                *(float2*)(p + 4) = make_float2(g4, g5);
            }
        }
        __syncthreads();

        // ---- update: 4 threads/coeff, 32 partials each, DPP combine ----
        if (upd) {
            float a = 0.0f, b = 0.0f;
#pragma unroll
            for (int j = 0; j < 16; ++j) {
                a += gpart[8 * j + chunk][ucol];
                b += gpart[8 * j + 4 + chunk][ucol];
            }
            float g = red1_g4(a + b);
            if (writer) {
                myc = fmaf(-0.1f, g, myc);
                sos[ucol] = myc;
            }
        }
        __syncthreads();
    }

    if (writer) out[u] = myc;
}

extern "C" void kernel_launch(void* const* d_in, const int* in_sizes, int n_in,
                              void* d_out, int out_size, void* d_ws, size_t ws_size,
                              hipStream_t stream) {
    const float* sos_in = (const float*)d_in[0];
    const float* target = (const float*)d_in[1];
    float* outp = (float*)d_out;
    hipLaunchKernelGGL(sgd_filter, dim3(1), dim3(TPB), 0, stream, sos_in, target, outp);
}